// Round 4
// baseline (189.039 us; speedup 1.0000x reference)
//
#include <hip/hip_runtime.h>

#define B_  4
#define S_  4096
#define DM  1024
#define DK  64
#define NSPLIT 8
#define KSPAN (S_ / NSPLIT)
#define QT  256                  // queries per flash block

typedef _Float16 half8  __attribute__((ext_vector_type(8)));
typedef _Float16 half4v __attribute__((ext_vector_type(4)));
typedef __fp16   fp16x2 __attribute__((ext_vector_type(2)));   // cvt_pkrtz return type
typedef float    floatx4 __attribute__((ext_vector_type(4)));

// 0.125 (1/sqrt(64)) * log2(e): softmax in exp2 domain
#define QSCALE 0.18033688011112042f
#define EXP2F(x) __builtin_amdgcn_exp2f(x)

// ---------------------------------------------------------------------------
// One-time W transpose+convert: Wt[proj][n][k] f16  <-  W[k][n] fp32.
// ---------------------------------------------------------------------------
__global__ __launch_bounds__(256) void wt_kernel(
    const float* __restrict__ WQ, const float* __restrict__ WK,
    const float* __restrict__ WV, _Float16* __restrict__ Wt)
{
    const int proj = blockIdx.y;
    const float* W = (proj == 0) ? WQ : (proj == 1) ? WK : WV;
    const int k0 = blockIdx.x * 64;
    const int t = threadIdx.x;
    __shared__ float T[64][68];

    #pragma unroll
    for (int p = 0; p < 4; p++) {
        int c = p * 256 + t;
        int k = c >> 4, n4 = (c & 15) * 4;
        float4 v = *(const float4*)(W + (size_t)(k0 + k) * DK + n4);
        T[k][n4 + 0] = v.x; T[k][n4 + 1] = v.y;
        T[k][n4 + 2] = v.z; T[k][n4 + 3] = v.w;
    }
    __syncthreads();

    const int n = t >> 2, kc = (t & 3) * 16;
    half8 h0, h1;
    #pragma unroll
    for (int j = 0; j < 8; j++) h0[j] = (_Float16)T[kc + j][n];
    #pragma unroll
    for (int j = 0; j < 8; j++) h1[j] = (_Float16)T[kc + 8 + j][n];
    _Float16* dst = Wt + ((size_t)proj * 64 + n) * DM + k0 + kc;
    *(half8*)(dst)     = h0;
    *(half8*)(dst + 8) = h1;
}

// ---------------------------------------------------------------------------
// Proj v2: LDS-free, barrier-free fused QKV projection.
//   X A-fragments: per-lane own row direct from global fp32 (HBM stream,
//   depth-2 prefetch), RTE convert to f16 in-register.
//   W B-fragments: direct from global Wt f16 (384 KB total, L1/L2-hot;
//   identical addresses across all waves and blocks).
//   No __shared__, no __syncthreads, no staging round-trips. Pace is the
//   X HBM stream (~1600 cy/CU/K-step vs ~500 cy compute).
// ---------------------------------------------------------------------------
__device__ inline half8 cvt8_rte(float4 a, float4 b)
{
    half8 h;
    h[0] = (_Float16)a.x; h[1] = (_Float16)a.y;
    h[2] = (_Float16)a.z; h[3] = (_Float16)a.w;
    h[4] = (_Float16)b.x; h[5] = (_Float16)b.y;
    h[6] = (_Float16)b.z; h[7] = (_Float16)b.w;
    return h;
}

__global__ __launch_bounds__(256) void proj_mfma_kernel(
    const float* __restrict__ X, const _Float16* __restrict__ Wt,
    const float* __restrict__ bQ, const float* __restrict__ bK,
    const float* __restrict__ bV,
    _Float16* __restrict__ Qh, _Float16* __restrict__ Kh,
    _Float16* __restrict__ Vt)
{
    const int r0   = blockIdx.x * 64;
    const int t    = threadIdx.x;
    const int wave = t >> 6, lane = t & 63;
    const int quad = lane >> 4, l15 = lane & 15;

    // each lane streams ITS OWN X row (no cross-wave reuse -> no LDS)
    const float* xrow = X + (size_t)(r0 + wave * 16 + l15) * DM;

    floatx4 acc[3][4];
    #pragma unroll
    for (int p = 0; p < 3; p++)
        #pragma unroll
        for (int nt = 0; nt < 4; nt++)
            acc[p][nt] = (floatx4){0.f, 0.f, 0.f, 0.f};

    // X fragment source for step k: 4 float4 at cols k*64 + {quad*8, quad*8+4,
    // 32+quad*8, 36+quad*8}. Depth-2 rotating prefetch, fully unrolled so all
    // indexing is static (no scratch).
#define LOADX(dst, k)                                                   \
    {                                                                   \
        const float* p_ = xrow + (k) * 64 + quad * 8;                   \
        dst[0] = *(const float4*)(p_);                                  \
        dst[1] = *(const float4*)(p_ + 4);                              \
        dst[2] = *(const float4*)(p_ + 32);                             \
        dst[3] = *(const float4*)(p_ + 36);                             \
    }

    float4 xA[4], xB[4], xC[4];
    LOADX(xA, 0);
    LOADX(xB, 1);

    #pragma unroll
    for (int kt = 0; kt < DM / 64; kt++) {
        if (kt + 2 < DM / 64) LOADX(xC, kt + 2);

        half8 xa0 = cvt8_rte(xA[0], xA[1]);
        half8 xa1 = cvt8_rte(xA[2], xA[3]);

        #pragma unroll
        for (int pr = 0; pr < 3; pr++) {
            #pragma unroll
            for (int nt = 0; nt < 4; nt++) {
                const _Float16* wp =
                    Wt + ((size_t)pr * 64 + nt * 16 + l15) * DM + kt * 64 + quad * 8;
                half8 bf0 = *(const half8*)(wp);
                half8 bf1 = *(const half8*)(wp + 32);
                floatx4 a = acc[pr][nt];
                a = __builtin_amdgcn_mfma_f32_16x16x32_f16(xa0, bf0, a, 0, 0, 0);
                a = __builtin_amdgcn_mfma_f32_16x16x32_f16(xa1, bf1, a, 0, 0, 0);
                acc[pr][nt] = a;
            }
        }

        #pragma unroll
        for (int j = 0; j < 4; j++) { xA[j] = xB[j]; xB[j] = xC[j]; }
    }
#undef LOADX

    float bqv[4], bkv[4], bvv[4];
    #pragma unroll
    for (int nt = 0; nt < 4; nt++) {
        bqv[nt] = bQ[nt * 16 + l15];
        bkv[nt] = bK[nt * 16 + l15];
        bvv[nt] = bV[nt * 16 + l15];
    }

    const int orow = r0 + wave * 16 + quad * 4;
    const int bidx = r0 >> 12;
    const int s0   = (r0 & (S_ - 1)) + wave * 16 + quad * 4;
    #pragma unroll
    for (int nt = 0; nt < 4; nt++) {
        const int d = nt * 16 + l15;
        #pragma unroll
        for (int i = 0; i < 4; i++) {
            Qh[(size_t)(orow + i) * DK + d] =
                (_Float16)((acc[0][nt][i] + bqv[nt]) * QSCALE);
            Kh[(size_t)(orow + i) * DK + d] =
                (_Float16)(acc[1][nt][i] + bkv[nt]);
        }
        half4v hv;
        #pragma unroll
        for (int i = 0; i < 4; i++)
            hv[i] = (_Float16)(acc[2][nt][i] + bvv[nt]);
        *(half4v*)(Vt + (size_t)bidx * DK * S_ + (size_t)d * S_ + s0) = hv;
    }
}

// ---------------------------------------------------------------------------
// Flash v5 (unchanged from R3): swapped-operand MFMA + key-permuted K staging
// = in-register P. DS ops/lane/tile 18; LDS 36.9KB.
// ---------------------------------------------------------------------------
__global__ __launch_bounds__(512, 4) void flash_mfma_kernel(
    const _Float16* __restrict__ Qh, const _Float16* __restrict__ Kh,
    const _Float16* __restrict__ Vt, _Float16* __restrict__ Oph,
    float* __restrict__ Lp)
{
    const int b     = blockIdx.y;
    const int q0    = blockIdx.x * QT;
    const int split = blockIdx.z;
    const int kbase = split * KSPAN;
    const int t     = threadIdx.x;
    const int wave  = t >> 6, lane = t & 63;
    const int quad  = lane >> 4, l15 = lane & 15;

    __shared__ __align__(16) _Float16 Ks[2][64 * 72];     // key-permuted rows
    __shared__ __align__(16) _Float16 Vs[2][64 * 72];     // [d][key]

    const _Float16* Qb = Qh + ((size_t)b * S_ + q0) * DK;
    const _Float16* Kb = Kh + ((size_t)b * S_ + kbase) * DK;
    const _Float16* Vb = Vt + (size_t)b * DK * S_ + kbase;

    half8 qf0[2], qf1[2];
    #pragma unroll
    for (int mt = 0; mt < 2; mt++) {
        const _Float16* qr = Qb + (size_t)(wave * 32 + mt * 16 + l15) * DK;
        qf0[mt] = *(const half8*)(qr + quad * 8);
        qf1[mt] = *(const half8*)(qr + 32 + quad * 8);
    }

    floatx4 acc[2][4];
    float rs[2];
    #pragma unroll
    for (int mt = 0; mt < 2; mt++) {
        #pragma unroll
        for (int nt = 0; nt < 4; nt++) acc[mt][nt] = (floatx4){0.f,0.f,0.f,0.f};
        rs[mt] = 0.f;
    }

    const int kr   = t >> 3, kcol = (t & 7) * 8;
    const int krP  = (kr & 32) | ((kr & 4) << 2) | ((kr & 24) >> 1) | (kr & 3);
    half8 kreg = *(const half8*)(Kb + (size_t)kr * DK + kcol);
    half8 vreg = *(const half8*)(Vb + (size_t)kr * S_ + kcol);
    *(half8*)&Ks[0][krP * 72 + kcol] = kreg;
    *(half8*)&Vs[0][kr  * 72 + kcol] = vreg;

    const int NT = KSPAN / 64;
    int cur = 0;
    for (int it = 0; it < NT; it++) {
        __syncthreads();

        if (it + 1 < NT) {
            const int kn = (it + 1) * 64;
            kreg = *(const half8*)(Kb + (size_t)(kn + kr) * DK + kcol);
            vreg = *(const half8*)(Vb + (size_t)kr * S_ + kn + kcol);
        }

        floatx4 sc[2][4];
        __builtin_amdgcn_s_setprio(1);
        #pragma unroll
        for (int nt = 0; nt < 4; nt++) {
            half8 kf0 = *(half8*)&Ks[cur][(nt * 16 + l15) * 72 + quad * 8];
            half8 kf1 = *(half8*)&Ks[cur][(nt * 16 + l15) * 72 + 32 + quad * 8];
            #pragma unroll
            for (int mt = 0; mt < 2; mt++) {
                floatx4 z = (floatx4){0.f, 0.f, 0.f, 0.f};
                z = __builtin_amdgcn_mfma_f32_16x16x32_f16(kf0, qf0[mt], z, 0, 0, 0);
                z = __builtin_amdgcn_mfma_f32_16x16x32_f16(kf1, qf1[mt], z, 0, 0, 0);
                sc[mt][nt] = z;
            }
        }
        __builtin_amdgcn_s_setprio(0);

        half8 pf0[2], pf1[2];
        #pragma unroll
        for (int mt = 0; mt < 2; mt++) {
            float pe[4][4];
            #pragma unroll
            for (int nt = 0; nt < 4; nt++)
                #pragma unroll
                for (int i = 0; i < 4; i++) {
                    pe[nt][i] = EXP2F(sc[mt][nt][i]);
                    rs[mt] += pe[nt][i];
                }
            fp16x2 c0 = __builtin_amdgcn_cvt_pkrtz(pe[0][0], pe[0][1]);
            fp16x2 c1 = __builtin_amdgcn_cvt_pkrtz(pe[0][2], pe[0][3]);
            fp16x2 c2 = __builtin_amdgcn_cvt_pkrtz(pe[1][0], pe[1][1]);
            fp16x2 c3 = __builtin_amdgcn_cvt_pkrtz(pe[1][2], pe[1][3]);
            pf0[mt] = (half8){(_Float16)c0[0], (_Float16)c0[1],
                              (_Float16)c1[0], (_Float16)c1[1],
                              (_Float16)c2[0], (_Float16)c2[1],
                              (_Float16)c3[0], (_Float16)c3[1]};
            fp16x2 c4 = __builtin_amdgcn_cvt_pkrtz(pe[2][0], pe[2][1]);
            fp16x2 c5 = __builtin_amdgcn_cvt_pkrtz(pe[2][2], pe[2][3]);
            fp16x2 c6 = __builtin_amdgcn_cvt_pkrtz(pe[3][0], pe[3][1]);
            fp16x2 c7 = __builtin_amdgcn_cvt_pkrtz(pe[3][2], pe[3][3]);
            pf1[mt] = (half8){(_Float16)c4[0], (_Float16)c4[1],
                              (_Float16)c5[0], (_Float16)c5[1],
                              (_Float16)c6[0], (_Float16)c6[1],
                              (_Float16)c7[0], (_Float16)c7[1]};
        }

        __builtin_amdgcn_s_setprio(1);
        #pragma unroll
        for (int nt = 0; nt < 4; nt++) {
            half8 vf0 = *(half8*)&Vs[cur][(nt * 16 + l15) * 72 + quad * 8];
            half8 vf1 = *(half8*)&Vs[cur][(nt * 16 + l15) * 72 + 32 + quad * 8];
            #pragma unroll
            for (int mt = 0; mt < 2; mt++) {
                floatx4 a = acc[mt][nt];
                a = __builtin_amdgcn_mfma_f32_16x16x32_f16(vf0, pf0[mt], a, 0, 0, 0);
                a = __builtin_amdgcn_mfma_f32_16x16x32_f16(vf1, pf1[mt], a, 0, 0, 0);
                acc[mt][nt] = a;
            }
        }
        __builtin_amdgcn_s_setprio(0);

        if (it + 1 < NT) {
            *(half8*)&Ks[cur ^ 1][krP * 72 + kcol] = kreg;
            *(half8*)&Vs[cur ^ 1][kr  * 72 + kcol] = vreg;
        }
        cur ^= 1;
    }

    const size_t prow = (size_t)split * B_ * S_ + (size_t)b * S_ + q0;
    #pragma unroll
    for (int mt = 0; mt < 2; mt++) {
        float r = rs[mt];
        r += __shfl_xor(r, 16, 64);
        r += __shfl_xor(r, 32, 64);
        const float inv = 1.0f / r;
        const size_t orow = prow + wave * 32 + mt * 16 + l15;
        #pragma unroll
        for (int nt = 0; nt < 4; nt++) {
            half4v hv;
            #pragma unroll
            for (int i = 0; i < 4; i++)
                hv[i] = (_Float16)(acc[mt][nt][i] * inv);
            *(half4v*)(Oph + orow * DK + nt * 16 + quad * 4) = hv;
        }
        if (quad == 0)
            Lp[orow] = r;
    }
}

// ---------------------------------------------------------------------------
// Combine: O[r] = sum_s l_s * Ohat_s[r] / sum_s l_s.  16 rows x 16 lanes.
// ---------------------------------------------------------------------------
__global__ __launch_bounds__(256) void combine_kernel(
    const _Float16* __restrict__ Oph, const float* __restrict__ Lp,
    float* __restrict__ O)
{
    const int r  = blockIdx.x * 16 + (threadIdx.x >> 4);
    const int d4 = (threadIdx.x & 15) * 4;
    const int NR = B_ * S_;

    float lw[NSPLIT], lsum = 0.f;
    #pragma unroll
    for (int s = 0; s < NSPLIT; s++) {
        lw[s] = Lp[(size_t)s * NR + r];
        lsum += lw[s];
    }
    const float inv = 1.0f / lsum;

    float o[4] = {0.f, 0.f, 0.f, 0.f};
    #pragma unroll
    for (int s = 0; s < NSPLIT; s++) {
        half4v h = *(const half4v*)(Oph + ((size_t)s * NR + r) * DK + d4);
        const float w = lw[s];
        #pragma unroll
        for (int j = 0; j < 4; j++) o[j] += w * (float)h[j];
    }
    float4 out;
    out.x = o[0] * inv; out.y = o[1] * inv;
    out.z = o[2] * inv; out.w = o[3] * inv;
    *(float4*)(O + (size_t)r * DK + d4) = out;
}

// ---------------------------------------------------------------------------
extern "C" void kernel_launch(void* const* d_in, const int* in_sizes, int n_in,
                              void* d_out, int out_size, void* d_ws, size_t ws_size,
                              hipStream_t stream)
{
    const float* X  = (const float*)d_in[0];
    // cultural path (d_in[1], d_in[8..10]) cancels in softmax -> unused
    const float* WQ = (const float*)d_in[2];
    const float* bQ = (const float*)d_in[3];
    const float* WK = (const float*)d_in[4];
    const float* bK = (const float*)d_in[5];
    const float* WV = (const float*)d_in[6];
    const float* bV = (const float*)d_in[7];

    char* ws = (char*)d_ws;
    _Float16* Qh  = (_Float16*)ws;  ws += (size_t)B_ * S_ * DK * 2;   // 2 MiB
    _Float16* Kh  = (_Float16*)ws;  ws += (size_t)B_ * S_ * DK * 2;
    _Float16* Vt  = (_Float16*)ws;  ws += (size_t)B_ * S_ * DK * 2;
    _Float16* Wt  = (_Float16*)ws;  ws += (size_t)3 * 64 * DM * 2;    // 384 KiB
    _Float16* Oph = (_Float16*)ws;  ws += (size_t)NSPLIT * B_ * S_ * DK * 2; // 16 MiB
    float* Lp     = (float*)ws;

    wt_kernel<<<dim3(DM / 64, 3), 256, 0, stream>>>(WQ, WK, WV, Wt);

    proj_mfma_kernel<<<dim3((B_ * S_) / 64), 256, 0, stream>>>(
        X, Wt, bQ, bK, bV, Qh, Kh, Vt);

    flash_mfma_kernel<<<dim3(S_ / QT, B_, NSPLIT), 512, 0, stream>>>(
        Qh, Kh, Vt, Oph, Lp);

    combine_kernel<<<dim3((B_ * S_) / 16), 256, 0, stream>>>(
        Oph, Lp, (float*)d_out);
}

// Round 5
// 153.766 us; speedup vs baseline: 1.2294x; 1.2294x over previous
//
#include <hip/hip_runtime.h>

#define B_  4
#define S_  4096
#define DM  1024
#define DK  64
#define NSPLIT 8
#define KSPAN (S_ / NSPLIT)
#define QT  256                  // queries per flash block

typedef _Float16 half8  __attribute__((ext_vector_type(8)));
typedef _Float16 half4v __attribute__((ext_vector_type(4)));
typedef __fp16   fp16x2 __attribute__((ext_vector_type(2)));   // cvt_pkrtz return type
typedef float    floatx4 __attribute__((ext_vector_type(4)));

// 0.125 (1/sqrt(64)) * log2(e): softmax in exp2 domain
#define QSCALE 0.18033688011112042f
#define EXP2F(x) __builtin_amdgcn_exp2f(x)

// ---------------------------------------------------------------------------
// One-time W transpose+convert: Wt[proj][n][k] f16  <-  W[k][n] fp32.
// ---------------------------------------------------------------------------
__global__ __launch_bounds__(256) void wt_kernel(
    const float* __restrict__ WQ, const float* __restrict__ WK,
    const float* __restrict__ WV, _Float16* __restrict__ Wt)
{
    const int proj = blockIdx.y;
    const float* W = (proj == 0) ? WQ : (proj == 1) ? WK : WV;
    const int k0 = blockIdx.x * 64;
    const int t = threadIdx.x;
    __shared__ float T[64][68];

    #pragma unroll
    for (int p = 0; p < 4; p++) {
        int c = p * 256 + t;
        int k = c >> 4, n4 = (c & 15) * 4;
        float4 v = *(const float4*)(W + (size_t)(k0 + k) * DK + n4);
        T[k][n4 + 0] = v.x; T[k][n4 + 1] = v.y;
        T[k][n4 + 2] = v.z; T[k][n4 + 3] = v.w;
    }
    __syncthreads();

    const int n = t >> 2, kc = (t & 3) * 16;
    half8 h0, h1;
    #pragma unroll
    for (int j = 0; j < 8; j++) h0[j] = (_Float16)T[kc + j][n];
    #pragma unroll
    for (int j = 0; j < 8; j++) h1[j] = (_Float16)T[kc + 8 + j][n];
    _Float16* dst = Wt + ((size_t)proj * 64 + n) * DM + k0 + kc;
    *(half8*)(dst)     = h0;
    *(half8*)(dst + 8) = h1;
}

__device__ inline half8 cvt8_rte(float4 a, float4 b)
{
    half8 h;
    h[0] = (_Float16)a.x; h[1] = (_Float16)a.y;
    h[2] = (_Float16)a.z; h[3] = (_Float16)a.w;
    h[4] = (_Float16)b.x; h[5] = (_Float16)b.y;
    h[6] = (_Float16)b.z; h[7] = (_Float16)b.w;
    return h;
}

// ---------------------------------------------------------------------------
// Proj v3: LDS-staged QKV projection, rebuilt for TLP + single barrier/step.
//   512 thr = 8 waves (2/SIMD): wave = (m-tile 0..3) x (N-half 0..1); each
//   wave computes 16 rows x 96 of the 192 output cols -> 12 MFMA/K-step.
//   Double-buffered Xs/Ws -> ONE barrier per K-step (16 total; v1 had 32).
//   Depth-1 register prefetch issued right after the barrier; the X HBM
//   stream (~1600 cy/step/CU) is the pace-setter and covers W L2 latency.
//   LDS 72 KB. W staged per block (24 KB/step) -> ~98 MB L2 traffic chip-
//   wide, absorbed at L2 BW.
// ---------------------------------------------------------------------------
__global__ __launch_bounds__(512) void proj_mfma_kernel(
    const float* __restrict__ X, const _Float16* __restrict__ Wt,
    const float* __restrict__ bQ, const float* __restrict__ bK,
    const float* __restrict__ bV,
    _Float16* __restrict__ Qh, _Float16* __restrict__ Kh,
    _Float16* __restrict__ Vt)
{
    const int r0   = blockIdx.x * 64;
    const int t    = threadIdx.x;
    const int wave = t >> 6, lane = t & 63;
    const int quad = lane >> 4, l15 = lane & 15;
    const int mt   = wave >> 1, nh = wave & 1;   // m-tile, N-half

    __shared__ __align__(16) _Float16 Xs[2][64 * 72];     // 18 KB
    __shared__ __align__(16) _Float16 Ws[2][192 * 72];    // 54 KB

    // staging coords
    const int xr = t >> 3, xc = (t & 7) * 8;              // X: 64 rows x 64 cols
    const float* xsrc = X + (size_t)(r0 + xr) * DM + xc;
    int wrow[3], wcol[3];                                  // W: 192 rows x 64 cols
    #pragma unroll
    for (int p = 0; p < 3; p++) {
        int c = p * 512 + t;
        wrow[p] = c >> 3; wcol[p] = (c & 7) * 8;
    }

    floatx4 acc[6];
    #pragma unroll
    for (int j = 0; j < 6; j++) acc[j] = (floatx4){0.f, 0.f, 0.f, 0.f};

    // prologue: load kt=0, stage into buf 0
    float4 xa4 = *(const float4*)(xsrc);
    float4 xb4 = *(const float4*)(xsrc + 4);
    half8 wr[3];
    #pragma unroll
    for (int p = 0; p < 3; p++)
        wr[p] = *(const half8*)(Wt + (size_t)wrow[p] * DM + wcol[p]);
    *(half8*)&Xs[0][xr * 72 + xc] = cvt8_rte(xa4, xb4);
    #pragma unroll
    for (int p = 0; p < 3; p++)
        *(half8*)&Ws[0][wrow[p] * 72 + wcol[p]] = wr[p];

    int cur = 0;
    #pragma unroll
    for (int kt = 0; kt < DM / 64; kt++) {
        __syncthreads();              // buf[cur] ready; iter kt-1 fully done

        if (kt + 1 < DM / 64) {       // prefetch next K-step into registers
            const int kn = (kt + 1) * 64;
            xa4 = *(const float4*)(xsrc + kn);
            xb4 = *(const float4*)(xsrc + kn + 4);
            #pragma unroll
            for (int p = 0; p < 3; p++)
                wr[p] = *(const half8*)(Wt + (size_t)wrow[p] * DM + kn + wcol[p]);
        }

        half8 xa0 = *(half8*)&Xs[cur][(mt * 16 + l15) * 72 + quad * 8];
        half8 xa1 = *(half8*)&Xs[cur][(mt * 16 + l15) * 72 + 32 + quad * 8];
        #pragma unroll
        for (int j = 0; j < 6; j++) {
            const int wn = (nh * 6 + j) * 16 + l15;       // flat Wt row
            half8 bf0 = *(half8*)&Ws[cur][wn * 72 + quad * 8];
            half8 bf1 = *(half8*)&Ws[cur][wn * 72 + 32 + quad * 8];
            floatx4 a = acc[j];
            a = __builtin_amdgcn_mfma_f32_16x16x32_f16(xa0, bf0, a, 0, 0, 0);
            a = __builtin_amdgcn_mfma_f32_16x16x32_f16(xa1, bf1, a, 0, 0, 0);
            acc[j] = a;
        }

        if (kt + 1 < DM / 64) {       // stage into other buffer (safe: all
            *(half8*)&Xs[cur ^ 1][xr * 72 + xc] = cvt8_rte(xa4, xb4);
            #pragma unroll             // readers of it passed barrier(kt))
            for (int p = 0; p < 3; p++)
                *(half8*)&Ws[cur ^ 1][wrow[p] * 72 + wcol[p]] = wr[p];
        }
        cur ^= 1;
    }

    // epilogue: nh=0 -> Q(nt0..3), K(nt0..1); nh=1 -> K(nt2..3), V(nt0..3)
    const int orow = r0 + mt * 16 + quad * 4;
    const int bidx = r0 >> 12;
    const int s0   = (r0 & (S_ - 1)) + mt * 16 + quad * 4;

    if (nh == 0) {
        #pragma unroll
        for (int j = 0; j < 4; j++) {
            const int d = j * 16 + l15;
            const float bq = bQ[d];
            #pragma unroll
            for (int i = 0; i < 4; i++)
                Qh[(size_t)(orow + i) * DK + d] =
                    (_Float16)((acc[j][i] + bq) * QSCALE);
        }
        #pragma unroll
        for (int j = 4; j < 6; j++) {
            const int d = (j - 4) * 16 + l15;
            const float bk = bK[d];
            #pragma unroll
            for (int i = 0; i < 4; i++)
                Kh[(size_t)(orow + i) * DK + d] =
                    (_Float16)(acc[j][i] + bk);
        }
    } else {
        #pragma unroll
        for (int j = 0; j < 2; j++) {
            const int d = (2 + j) * 16 + l15;
            const float bk = bK[d];
            #pragma unroll
            for (int i = 0; i < 4; i++)
                Kh[(size_t)(orow + i) * DK + d] =
                    (_Float16)(acc[j][i] + bk);
        }
        #pragma unroll
        for (int j = 2; j < 6; j++) {
            const int d = (j - 2) * 16 + l15;
            const float bv = bV[d];
            half4v hv;
            #pragma unroll
            for (int i = 0; i < 4; i++)
                hv[i] = (_Float16)(acc[j][i] + bv);
            *(half4v*)(Vt + (size_t)bidx * DK * S_ + (size_t)d * S_ + s0) = hv;
        }
    }
}

// ---------------------------------------------------------------------------
// Flash v5 (unchanged from R3): swapped-operand MFMA + key-permuted K staging
// = in-register P. DS ops/lane/tile 18; LDS 36.9KB.
// ---------------------------------------------------------------------------
__global__ __launch_bounds__(512, 4) void flash_mfma_kernel(
    const _Float16* __restrict__ Qh, const _Float16* __restrict__ Kh,
    const _Float16* __restrict__ Vt, _Float16* __restrict__ Oph,
    float* __restrict__ Lp)
{
    const int b     = blockIdx.y;
    const int q0    = blockIdx.x * QT;
    const int split = blockIdx.z;
    const int kbase = split * KSPAN;
    const int t     = threadIdx.x;
    const int wave  = t >> 6, lane = t & 63;
    const int quad  = lane >> 4, l15 = lane & 15;

    __shared__ __align__(16) _Float16 Ks[2][64 * 72];     // key-permuted rows
    __shared__ __align__(16) _Float16 Vs[2][64 * 72];     // [d][key]

    const _Float16* Qb = Qh + ((size_t)b * S_ + q0) * DK;
    const _Float16* Kb = Kh + ((size_t)b * S_ + kbase) * DK;
    const _Float16* Vb = Vt + (size_t)b * DK * S_ + kbase;

    half8 qf0[2], qf1[2];
    #pragma unroll
    for (int mt = 0; mt < 2; mt++) {
        const _Float16* qr = Qb + (size_t)(wave * 32 + mt * 16 + l15) * DK;
        qf0[mt] = *(const half8*)(qr + quad * 8);
        qf1[mt] = *(const half8*)(qr + 32 + quad * 8);
    }

    floatx4 acc[2][4];
    float rs[2];
    #pragma unroll
    for (int mt = 0; mt < 2; mt++) {
        #pragma unroll
        for (int nt = 0; nt < 4; nt++) acc[mt][nt] = (floatx4){0.f,0.f,0.f,0.f};
        rs[mt] = 0.f;
    }

    const int kr   = t >> 3, kcol = (t & 7) * 8;
    const int krP  = (kr & 32) | ((kr & 4) << 2) | ((kr & 24) >> 1) | (kr & 3);
    half8 kreg = *(const half8*)(Kb + (size_t)kr * DK + kcol);
    half8 vreg = *(const half8*)(Vb + (size_t)kr * S_ + kcol);
    *(half8*)&Ks[0][krP * 72 + kcol] = kreg;
    *(half8*)&Vs[0][kr  * 72 + kcol] = vreg;

    const int NT = KSPAN / 64;
    int cur = 0;
    for (int it = 0; it < NT; it++) {
        __syncthreads();

        if (it + 1 < NT) {
            const int kn = (it + 1) * 64;
            kreg = *(const half8*)(Kb + (size_t)(kn + kr) * DK + kcol);
            vreg = *(const half8*)(Vb + (size_t)kr * S_ + kn + kcol);
        }

        floatx4 sc[2][4];
        __builtin_amdgcn_s_setprio(1);
        #pragma unroll
        for (int nt = 0; nt < 4; nt++) {
            half8 kf0 = *(half8*)&Ks[cur][(nt * 16 + l15) * 72 + quad * 8];
            half8 kf1 = *(half8*)&Ks[cur][(nt * 16 + l15) * 72 + 32 + quad * 8];
            #pragma unroll
            for (int mt = 0; mt < 2; mt++) {
                floatx4 z = (floatx4){0.f, 0.f, 0.f, 0.f};
                z = __builtin_amdgcn_mfma_f32_16x16x32_f16(kf0, qf0[mt], z, 0, 0, 0);
                z = __builtin_amdgcn_mfma_f32_16x16x32_f16(kf1, qf1[mt], z, 0, 0, 0);
                sc[mt][nt] = z;
            }
        }
        __builtin_amdgcn_s_setprio(0);

        half8 pf0[2], pf1[2];
        #pragma unroll
        for (int mt = 0; mt < 2; mt++) {
            float pe[4][4];
            #pragma unroll
            for (int nt = 0; nt < 4; nt++)
                #pragma unroll
                for (int i = 0; i < 4; i++) {
                    pe[nt][i] = EXP2F(sc[mt][nt][i]);
                    rs[mt] += pe[nt][i];
                }
            fp16x2 c0 = __builtin_amdgcn_cvt_pkrtz(pe[0][0], pe[0][1]);
            fp16x2 c1 = __builtin_amdgcn_cvt_pkrtz(pe[0][2], pe[0][3]);
            fp16x2 c2 = __builtin_amdgcn_cvt_pkrtz(pe[1][0], pe[1][1]);
            fp16x2 c3 = __builtin_amdgcn_cvt_pkrtz(pe[1][2], pe[1][3]);
            pf0[mt] = (half8){(_Float16)c0[0], (_Float16)c0[1],
                              (_Float16)c1[0], (_Float16)c1[1],
                              (_Float16)c2[0], (_Float16)c2[1],
                              (_Float16)c3[0], (_Float16)c3[1]};
            fp16x2 c4 = __builtin_amdgcn_cvt_pkrtz(pe[2][0], pe[2][1]);
            fp16x2 c5 = __builtin_amdgcn_cvt_pkrtz(pe[2][2], pe[2][3]);
            fp16x2 c6 = __builtin_amdgcn_cvt_pkrtz(pe[3][0], pe[3][1]);
            fp16x2 c7 = __builtin_amdgcn_cvt_pkrtz(pe[3][2], pe[3][3]);
            pf1[mt] = (half8){(_Float16)c4[0], (_Float16)c4[1],
                              (_Float16)c5[0], (_Float16)c5[1],
                              (_Float16)c6[0], (_Float16)c6[1],
                              (_Float16)c7[0], (_Float16)c7[1]};
        }

        __builtin_amdgcn_s_setprio(1);
        #pragma unroll
        for (int nt = 0; nt < 4; nt++) {
            half8 vf0 = *(half8*)&Vs[cur][(nt * 16 + l15) * 72 + quad * 8];
            half8 vf1 = *(half8*)&Vs[cur][(nt * 16 + l15) * 72 + 32 + quad * 8];
            #pragma unroll
            for (int mt = 0; mt < 2; mt++) {
                floatx4 a = acc[mt][nt];
                a = __builtin_amdgcn_mfma_f32_16x16x32_f16(vf0, pf0[mt], a, 0, 0, 0);
                a = __builtin_amdgcn_mfma_f32_16x16x32_f16(vf1, pf1[mt], a, 0, 0, 0);
                acc[mt][nt] = a;
            }
        }
        __builtin_amdgcn_s_setprio(0);

        if (it + 1 < NT) {
            *(half8*)&Ks[cur ^ 1][krP * 72 + kcol] = kreg;
            *(half8*)&Vs[cur ^ 1][kr  * 72 + kcol] = vreg;
        }
        cur ^= 1;
    }

    const size_t prow = (size_t)split * B_ * S_ + (size_t)b * S_ + q0;
    #pragma unroll
    for (int mt = 0; mt < 2; mt++) {
        float r = rs[mt];
        r += __shfl_xor(r, 16, 64);
        r += __shfl_xor(r, 32, 64);
        const float inv = 1.0f / r;
        const size_t orow = prow + wave * 32 + mt * 16 + l15;
        #pragma unroll
        for (int nt = 0; nt < 4; nt++) {
            half4v hv;
            #pragma unroll
            for (int i = 0; i < 4; i++)
                hv[i] = (_Float16)(acc[mt][nt][i] * inv);
            *(half4v*)(Oph + orow * DK + nt * 16 + quad * 4) = hv;
        }
        if (quad == 0)
            Lp[orow] = r;
    }
}

// ---------------------------------------------------------------------------
// Combine: O[r] = sum_s l_s * Ohat_s[r] / sum_s l_s.  16 rows x 16 lanes.
// ---------------------------------------------------------------------------
__global__ __launch_bounds__(256) void combine_kernel(
    const _Float16* __restrict__ Oph, const float* __restrict__ Lp,
    float* __restrict__ O)
{
    const int r  = blockIdx.x * 16 + (threadIdx.x >> 4);
    const int d4 = (threadIdx.x & 15) * 4;
    const int NR = B_ * S_;

    float lw[NSPLIT], lsum = 0.f;
    #pragma unroll
    for (int s = 0; s < NSPLIT; s++) {
        lw[s] = Lp[(size_t)s * NR + r];
        lsum += lw[s];
    }
    const float inv = 1.0f / lsum;

    float o[4] = {0.f, 0.f, 0.f, 0.f};
    #pragma unroll
    for (int s = 0; s < NSPLIT; s++) {
        half4v h = *(const half4v*)(Oph + ((size_t)s * NR + r) * DK + d4);
        const float w = lw[s];
        #pragma unroll
        for (int j = 0; j < 4; j++) o[j] += w * (float)h[j];
    }
    float4 out;
    out.x = o[0] * inv; out.y = o[1] * inv;
    out.z = o[2] * inv; out.w = o[3] * inv;
    *(float4*)(O + (size_t)r * DK + d4) = out;
}

// ---------------------------------------------------------------------------
extern "C" void kernel_launch(void* const* d_in, const int* in_sizes, int n_in,
                              void* d_out, int out_size, void* d_ws, size_t ws_size,
                              hipStream_t stream)
{
    const float* X  = (const float*)d_in[0];
    // cultural path (d_in[1], d_in[8..10]) cancels in softmax -> unused
    const float* WQ = (const float*)d_in[2];
    const float* bQ = (const float*)d_in[3];
    const float* WK = (const float*)d_in[4];
    const float* bK = (const float*)d_in[5];
    const float* WV = (const float*)d_in[6];
    const float* bV = (const float*)d_in[7];

    char* ws = (char*)d_ws;
    _Float16* Qh  = (_Float16*)ws;  ws += (size_t)B_ * S_ * DK * 2;   // 2 MiB
    _Float16* Kh  = (_Float16*)ws;  ws += (size_t)B_ * S_ * DK * 2;
    _Float16* Vt  = (_Float16*)ws;  ws += (size_t)B_ * S_ * DK * 2;
    _Float16* Wt  = (_Float16*)ws;  ws += (size_t)3 * 64 * DM * 2;    // 384 KiB
    _Float16* Oph = (_Float16*)ws;  ws += (size_t)NSPLIT * B_ * S_ * DK * 2; // 16 MiB
    float* Lp     = (float*)ws;

    wt_kernel<<<dim3(DM / 64, 3), 256, 0, stream>>>(WQ, WK, WV, Wt);

    proj_mfma_kernel<<<dim3((B_ * S_) / 64), 512, 0, stream>>>(
        X, Wt, bQ, bK, bV, Qh, Kh, Vt);

    flash_mfma_kernel<<<dim3(S_ / QT, B_, NSPLIT), 512, 0, stream>>>(
        Qh, Kh, Vt, Oph, Lp);

    combine_kernel<<<dim3((B_ * S_) / 16), 256, 0, stream>>>(
        Oph, Lp, (float*)d_out);
}